// Round 20
// baseline (4007.955 us; speedup 1.0000x reference)
//
#include <hip/hip_runtime.h>

#define SEQ 512
#define DM 1024
#define NH 8
#define HD 128
#define FFN 4096
#define NL 4
#define NB 8

typedef __attribute__((ext_vector_type(8))) _Float16 half8v;
typedef __attribute__((ext_vector_type(8))) unsigned short ushort8v;
typedef __attribute__((ext_vector_type(4))) float float4v;

__device__ __forceinline__ unsigned short f2h(float f) {
  _Float16 h = (_Float16)f;
  return *(unsigned short*)&h;
}
__device__ __forceinline__ float h2f(unsigned short u) {
  _Float16 h = *(_Float16*)&u;
  return (float)h;
}

// ---------------- prep: sc table (blocks 0..127) + x copy/fp16 shadow (blocks 128..) ----------------
__global__ void prep_kernel(float* __restrict__ sc,
                            const float* __restrict__ in, float* __restrict__ xout,
                            unsigned short* __restrict__ xh) {
  if (blockIdx.x < 128) {
    int idx = blockIdx.x * 256 + threadIdx.x;
    int q = idx >> 6, c = idx & 63;
    double a = exp(-(double)c * (9.210340371976184 / 63.0));  // ln(10000)/63
    double p = (double)q * a;
    sc[q * 128 + c] = (float)sin(p);
    sc[q * 128 + 64 + c] = (float)cos(p);
  } else {
    int i = (blockIdx.x - 128) * 256 + threadIdx.x;
    float4 v = ((const float4*)in)[i];
    ((float4*)xout)[i] = v;
    ushort4 u;
    u.x = f2h(v.x); u.y = f2h(v.y); u.z = f2h(v.z); u.w = f2h(v.w);
    ((ushort4*)xh)[i] = u;
  }
}

// ---------------- batched weight transpose+cvt for one layer: qkv_w, w1, w2 ----------------
__global__ __launch_bounds__(256) void transpose_cvt3(
    const float* __restrict__ qw, const float* __restrict__ w1,
    const float* __restrict__ w2,
    unsigned short* __restrict__ wqt, unsigned short* __restrict__ w1t,
    unsigned short* __restrict__ w2t)
{
  __shared__ float t[32][33];
  int id = blockIdx.x;
  const float* in;
  unsigned short* out;
  int K, N, loc;
  if (id < 3072)      { in = qw; out = wqt; K = 1024; N = 3072; loc = id; }
  else if (id < 7168) { in = w1; out = w1t; K = 1024; N = 4096; loc = id - 3072; }
  else                { in = w2; out = w2t; K = 4096; N = 1024; loc = id - 7168; }
  int nx = N >> 5;
  int n0 = (loc % nx) * 32, k0 = (loc / nx) * 32;
  int c = threadIdx.x & 31, r = threadIdx.x >> 5;
#pragma unroll
  for (int i = 0; i < 32; i += 8)
    t[r + i][c] = in[(long long)(k0 + r + i) * N + n0 + c];
  __syncthreads();
#pragma unroll
  for (int i = 0; i < 32; i += 8)
    out[(long long)(n0 + r + i) * K + k0 + c] = f2h(t[c][r + i]);
}

// ---------------- staging: R rows x 64 cols fp16, st_16x32 swizzle, 16B DMA ----------------
template<int R, int T>
__device__ __forceinline__ void stage_tile(
    const unsigned short* __restrict__ g, long long ld, int k0,
    unsigned short* lds, int tid) {
#pragma unroll
  for (int i = 0; i < R * 64 / 8 / T; i++) {
    int p = i * T + tid;
    int row = p >> 3, cs = p & 7;
    int c = cs ^ (row & 7);
    const unsigned short* src = g + (long long)row * ld + k0 + c * 8;
    __builtin_amdgcn_global_load_lds(
        (const __attribute__((address_space(1))) void*)src,
        (__attribute__((address_space(3))) void*)(lds + p * 8),
        16, 0, 0);
  }
}

// 256 rows x 32 K-cols region; chunk swizzle c = cs ^ ((row>>1)&3); 2 loads/thread @512thr
__device__ __forceinline__ void stageK(
    const unsigned short* __restrict__ g, long long ld, int k0,
    unsigned short* lds, int tid) {
#pragma unroll
  for (int i = 0; i < 2; i++) {
    int p = i * 512 + tid;              // 0..1023 16B slots
    int row = p >> 2, cs = p & 3;
    int c = cs ^ ((row >> 1) & 3);
    const unsigned short* src = g + (long long)row * ld + k0 + c * 8;
    __builtin_amdgcn_global_load_lds(
        (const __attribute__((address_space(1))) void*)src,
        (__attribute__((address_space(3))) void*)(lds + p * 8),
        16, 0, 0);
  }
}

// ---------------- reg-staged 128x64 tile: global->VGPR then VGPR->LDS ----------------
__device__ __forceinline__ void load_stage128(
    const unsigned short* __restrict__ g, long long ld, int k0, int tid, ushort8v* v) {
#pragma unroll
  for (int i = 0; i < 2; i++) {
    int p = i * 512 + tid;
    int row = p >> 3, cs = p & 7;
    int c = cs ^ (row & 7);
    v[i] = *(const ushort8v*)(g + (long long)row * ld + k0 + c * 8);
  }
}
__device__ __forceinline__ void write_stage128(
    unsigned short* St, int tid, const ushort8v* v) {
#pragma unroll
  for (int i = 0; i < 2; i++)
    *(ushort8v*)(St + (i * 512 + tid) * 8) = v[i];
}

// ---------------- 256x256 fp16 MFMA GEMM: BK=32, dbuf (64KB LDS -> 2 blocks/CU) ----------------
// 512 threads = 8 waves (2M x 4N); per-wave 128x64 output = 8x4 16x16 frags.
// Per tile: issue t+1's 4 loads, vmcnt(4) (t landed, t+1 in flight), barrier,
// 12 ds_read + 32 MFMA, barrier. 2 blocks/CU so barrier stalls overlap cross-block.
template<int BIAS, int RELU, int OUTH>
__global__ __launch_bounds__(512, 4) void gemm256(
    const unsigned short* __restrict__ A, int lda, long long sAz,
    const unsigned short* __restrict__ Bt, int ldb, long long sBz,
    const float* __restrict__ bias,
    void* __restrict__ Cv, int ldc, long long sCz,
    int K) {
  __shared__ __align__(16) unsigned short As[2][256 * 32];
  __shared__ __align__(16) unsigned short Bs[2][256 * 32];
  const int tid = threadIdx.x, lane = tid & 63, w = tid >> 6;
  const int wm = w >> 2, wn = w & 3;
  const int l15 = lane & 15, l4 = lane >> 4;
  const int gx = gridDim.x, gy = gridDim.y;
  int nwg = gx * gy * gridDim.z;
  int lin = (blockIdx.z * gy + blockIdx.y) * gx + blockIdx.x;
  int swz = (lin & 7) * (nwg >> 3) + (lin >> 3);
  int bx = swz % gx;
  int t2 = swz / gx;
  int by = t2 % gy;
  int z  = t2 / gy;
  const unsigned short* Ag = A + (long long)z * sAz + (long long)by * 256 * lda;
  const unsigned short* Bg = Bt + (long long)z * sBz + (long long)bx * 256 * ldb;

  float4v acc[8][4] = {};
  const int nt = K >> 5;
  stageK(Ag, lda, 0, As[0], tid);
  stageK(Bg, ldb, 0, Bs[0], tid);
  int cur = 0;
  for (int t = 0; t < nt; t++) {
    if (t + 1 < nt) {
      stageK(Ag, lda, (t + 1) << 5, As[cur ^ 1], tid);
      stageK(Bg, ldb, (t + 1) << 5, Bs[cur ^ 1], tid);
      asm volatile("s_waitcnt vmcnt(4)" ::: "memory");
    } else {
      asm volatile("s_waitcnt vmcnt(0)" ::: "memory");
    }
    asm volatile("s_barrier" ::: "memory");     // tile t (buf cur) visible to all waves
    {
      half8v af[8], bf[4];
#pragma unroll
      for (int m = 0; m < 8; m++) {
        int row = wm * 128 + m * 16 + l15;
        int ch = l4 ^ ((row >> 1) & 3);
        af[m] = *(const half8v*)&As[cur][row * 32 + ch * 8];
      }
#pragma unroll
      for (int n = 0; n < 4; n++) {
        int row = wn * 64 + n * 16 + l15;
        int ch = l4 ^ ((row >> 1) & 3);
        bf[n] = *(const half8v*)&Bs[cur][row * 32 + ch * 8];
      }
      __builtin_amdgcn_s_setprio(1);
#pragma unroll
      for (int m = 0; m < 8; m++)
#pragma unroll
        for (int n = 0; n < 4; n++)
          acc[m][n] = __builtin_amdgcn_mfma_f32_16x16x32_f16(af[m], bf[n], acc[m][n], 0, 0, 0);
      __builtin_amdgcn_s_setprio(0);
    }
    asm volatile("s_barrier" ::: "memory");     // all reads of buf cur done before re-stage
    cur ^= 1;
  }
#pragma unroll
  for (int n = 0; n < 4; n++) {
    int ccol = bx * 256 + wn * 64 + n * 16 + l15;
    float bv = BIAS ? bias[ccol] : 0.f;
#pragma unroll
    for (int m = 0; m < 8; m++) {
      int crow0 = by * 256 + wm * 128 + m * 16 + l4 * 4;
#pragma unroll
      for (int j = 0; j < 4; j++) {
        float v = acc[m][n][j] + bv;
        if (RELU) v = fmaxf(v, 0.f);
        long long off = (long long)z * sCz + (long long)(crow0 + j) * ldc + ccol;
        if (OUTH) ((unsigned short*)Cv)[off] = f2h(v);
        else      ((float*)Cv)[off] = v;
      }
    }
  }
}

// ---------------- merged attention prep: build_aug (bx<256) + V transpose (bx>=256) ----------------
__global__ __launch_bounds__(256) void build_attn(
    const unsigned short* __restrict__ qkv_h,
    const float* __restrict__ rr, const float* __restrict__ rw,
    const float* __restrict__ sc,
    unsigned short* __restrict__ Ahat, unsigned short* __restrict__ Bhat,
    unsigned short* __restrict__ Vt)
{
  const int z = blockIdx.y, b = z >> 3, h = z & 7;
  if (blockIdx.x < 256) {
    const int r = threadIdx.x >> 7, lane = threadIdx.x & 127;
    const int q = blockIdx.x * 2 + r;
    __shared__ float Qf[2][128], Kf[2][128], SC[2][128];
    const unsigned short* row = qkv_h + ((long long)(b * SEQ + q)) * 3072 + h * HD;
    float qv = h2f(row[lane]);
    float kv = h2f(row[DM + lane]);
    Qf[r][lane] = qv + rw[h * HD + lane];
    Kf[r][lane] = kv;
    SC[r][lane] = sc[q * 128 + lane];
    __syncthreads();
    unsigned short* Arow = Ahat + ((long long)z * SEQ + q) * 384;
    unsigned short* Brow = Bhat + ((long long)z * SEQ + q) * 384;
    Arow[lane] = f2h(qv + rr[h * HD + lane]);
    Brow[lane] = f2h(kv);
    if (lane < 64) {
      float S = SC[r][lane], C = SC[r][64 + lane];
      Arow[128 + lane] = f2h(Qf[r][lane] * C + Qf[r][64 + lane] * S);
      Arow[256 + lane] = f2h(S);
      Brow[128 + lane] = f2h(S);
      Brow[256 + lane] = f2h(Kf[r][lane] * C + Kf[r][64 + lane] * S);
    } else {
      int c = lane - 64;
      float S = SC[r][c], C = SC[r][lane];
      Arow[192 + c] = f2h(Qf[r][lane] * C - Qf[r][c] * S);
      Arow[320 + c] = f2h(C);
      Brow[192 + c] = f2h(C);
      Brow[320 + c] = f2h(Kf[r][lane] * C - Kf[r][c] * S);
    }
  } else {
    __shared__ unsigned short t[32][33];
    int tile = blockIdx.x - 256;            // 64 tiles: 4 (d) x 16 (j)
    const int d0 = (tile & 3) * 32, j0 = (tile >> 2) * 32;
    const int c = threadIdx.x & 31, r = threadIdx.x >> 5;
#pragma unroll
    for (int i = 0; i < 32; i += 8)
      t[r + i][c] = qkv_h[((long long)(b * SEQ + j0 + r + i)) * 3072 + 2 * DM + h * HD + d0 + c];
    __syncthreads();
#pragma unroll
    for (int i = 0; i < 32; i += 8)
      Vt[(long long)z * HD * SEQ + (long long)(d0 + r + i) * SEQ + j0 + c] = t[c][r + i];
  }
}

// ---------------- fused attention: reg-staged pipeline, raw barriers, no vmcnt drain ----------------
__global__ __launch_bounds__(512, 4) void attn_fused(
    const unsigned short* __restrict__ Ahat,
    const unsigned short* __restrict__ Bhat,
    const unsigned short* __restrict__ Vt,
    const int* __restrict__ mask,
    unsigned short* __restrict__ out)
{
  __shared__ __align__(16) unsigned short S[64 * 512];
  __shared__ __align__(16) unsigned short St[128 * 64];
  const int tid = threadIdx.x, lane = tid & 63, w = tid >> 6;
  const int wr = w >> 1, wc = w & 1;
  const int l15 = lane & 15, l4 = lane >> 4;
  int lin = blockIdx.z * gridDim.x + blockIdx.x;
  int nwg = gridDim.x * gridDim.z;
  int swz = (lin & 7) * (nwg >> 3) + (lin >> 3);
  int qt = swz % gridDim.x, z = swz / gridDim.x;
  const int b = z >> 3, h = z & 7;
  const int q0 = qt * 64;

  half8v qf[12];
  {
    const unsigned short* Ar = Ahat + ((long long)z * SEQ + q0 + wr * 16 + l15) * 384;
#pragma unroll
    for (int k = 0; k < 12; k++)
      qf[k] = *(const half8v*)&Ar[k * 32 + l4 * 8];
  }

  // ---- phase 1: S (64 x 512) fp16 into XOR-swizzled LDS; B-tiles reg-staged ----
  ushort8v stg[2];
  load_stage128(Bhat + ((long long)z * SEQ) * 384, 384, 0, tid, stg);
#pragma unroll
  for (int jt = 0; jt < 4; jt++) {
    float4v acc[4] = {};
#pragma unroll
    for (int k6 = 0; k6 < 6; k6++) {
      __builtin_amdgcn_s_barrier();                 // St free (prev compute done)
      write_stage128(St, tid, stg);
      int ns = jt * 6 + k6 + 1;
      if (ns < 24) {
        const unsigned short* Bg = Bhat + ((long long)z * SEQ + (ns / 6) * 128) * 384;
        load_stage128(Bg, 384, (ns % 6) * 64, tid, stg);
      }
      asm volatile("s_waitcnt lgkmcnt(0)" ::: "memory");
      __builtin_amdgcn_s_barrier();                 // St visible (vmcnt NOT drained)
      __builtin_amdgcn_s_setprio(1);
#pragma unroll
      for (int kk = 0; kk < 2; kk++) {
        int kidx = k6 * 2 + kk;
#pragma unroll
        for (int n = 0; n < 4; n++) {
          int row = wc * 64 + n * 16 + l15;
          int cs = (kk * 4 + l4) ^ (row & 7);
          half8v bf = *(const half8v*)&St[row * 64 + cs * 8];
          acc[n] = __builtin_amdgcn_mfma_f32_16x16x32_f16(qf[kidx], bf, acc[n], 0, 0, 0);
        }
      }
      __builtin_amdgcn_s_setprio(0);
    }
#pragma unroll
    for (int n = 0; n < 4; n++) {
      int col = jt * 128 + wc * 64 + n * 16 + l15;
#pragma unroll
      for (int j = 0; j < 4; j++) {
        int row = wr * 16 + l4 * 4 + j;
        int byte = (row * 512 + col) * 2;
        byte ^= (row & 7) << 4;
        *(unsigned short*)((char*)S + byte) = f2h(acc[n][j]);
      }
    }
  }

  // prefetch V tile 0 (latency hides under softmax)
  const unsigned short* Vg = Vt + (long long)z * HD * SEQ;
  load_stage128(Vg, 512, 0, tid, stg);

  asm volatile("s_waitcnt lgkmcnt(0)" ::: "memory");  // S writes done
  __builtin_amdgcn_s_barrier();

  // ---- phase 2: mask bias + in-LDS softmax (interleaved, bank-friendly) ----
  float* bias = (float*)St;          // 512 floats
  float* Linv = (float*)St + 512;    // 64 floats
  if (tid < 128) {
    int4 mk = ((const int4*)(mask + (size_t)b * SEQ))[tid];
    float4 bv;
    bv.x = mk.x ? 0.f : -1e30f;
    bv.y = mk.y ? 0.f : -1e30f;
    bv.z = mk.z ? 0.f : -1e30f;
    bv.w = mk.w ? 0.f : -1e30f;
    ((float4*)bias)[tid] = bv;
  }
  asm volatile("s_waitcnt lgkmcnt(0)" ::: "memory");
  __builtin_amdgcn_s_barrier();
  {
    const int row = tid >> 3;
    const int c8 = tid & 7;
    float mx = -1e30f;
#pragma unroll
    for (int i = 0; i < 8; i++) {
      int col = i * 64 + c8 * 8;
      int byte = (row * 512 + col) * 2;
      byte ^= (row & 7) << 4;
      ushort8v u = *(const ushort8v*)((const char*)S + byte);
      const float* bp = bias + col;
#pragma unroll
      for (int e = 0; e < 8; e++)
        mx = fmaxf(mx, h2f(u[e]) + bp[e]);
    }
    mx = fmaxf(mx, __shfl_xor(mx, 1));
    mx = fmaxf(mx, __shfl_xor(mx, 2));
    mx = fmaxf(mx, __shfl_xor(mx, 4));
    float sum = 0.f;
#pragma unroll
    for (int i = 0; i < 8; i++) {
      int col = i * 64 + c8 * 8;
      int byte = (row * 512 + col) * 2;
      byte ^= (row & 7) << 4;
      ushort8v u = *(const ushort8v*)((const char*)S + byte);
      const float* bp = bias + col;
#pragma unroll
      for (int e = 0; e < 8; e++) {
        float ev = __expf(h2f(u[e]) + bp[e] - mx);
        sum += ev;
        u[e] = f2h(ev);
      }
      *(ushort8v*)((char*)S + byte) = u;
    }
    sum += __shfl_xor(sum, 1);
    sum += __shfl_xor(sum, 2);
    sum += __shfl_xor(sum, 4);
    if (c8 == 0) Linv[row] = 1.f / sum;
  }
  asm volatile("s_waitcnt lgkmcnt(0)" ::: "memory");
  __builtin_amdgcn_s_barrier();
  float rs[4];
#pragma unroll
  for (int j = 0; j < 4; j++) rs[j] = Linv[wr * 16 + l4 * 4 + j];
  asm volatile("s_waitcnt lgkmcnt(0)" ::: "memory");  // Linv reads complete before St reuse

  // ---- phase 3: O = P-hat @ Vt^T; V-tiles reg-staged ----
  float4v oacc[4] = {};
#pragma unroll
  for (int k8 = 0; k8 < 8; k8++) {
    __builtin_amdgcn_s_barrier();                 // St free
    write_stage128(St, tid, stg);
    if (k8 + 1 < 8) load_stage128(Vg, 512, (k8 + 1) * 64, tid, stg);
    asm volatile("s_waitcnt lgkmcnt(0)" ::: "memory");
    __builtin_amdgcn_s_barrier();                 // St visible
    __builtin_amdgcn_s_setprio(1);
#pragma unroll
    for (int kk = 0; kk < 2; kk++) {
      int prow = wr * 16 + l15;
      int pb = (prow * 512 + k8 * 64 + kk * 32 + l4 * 8) * 2;
      pb ^= (prow & 7) << 4;
      half8v af = *(const half8v*)((const char*)S + pb);
#pragma unroll
      for (int n = 0; n < 4; n++) {
        int row = wc * 64 + n * 16 + l15;
        int cs = (kk * 4 + l4) ^ (row & 7);
        half8v bf = *(const half8v*)&St[row * 64 + cs * 8];
        oacc[n] = __builtin_amdgcn_mfma_f32_16x16x32_f16(af, bf, oacc[n], 0, 0, 0);
      }
    }
    __builtin_amdgcn_s_setprio(0);
  }
#pragma unroll
  for (int j = 0; j < 4; j++) {
    int row = q0 + wr * 16 + l4 * 4 + j;
#pragma unroll
    for (int n = 0; n < 4; n++) {
      int col = h * HD + wc * 64 + n * 16 + l15;
      out[((long long)(b * SEQ + row)) * DM + col] = f2h(oacc[n][j] * rs[j]);
    }
  }
}

// ---------------- x = LayerNorm(x + a16)*g + b, in-place, + fp16 shadow ----------------
__global__ __launch_bounds__(256) void add_ln_cvt(
    float* __restrict__ x, const unsigned short* __restrict__ a,
    const float* __restrict__ g, const float* __restrict__ bt,
    unsigned short* __restrict__ xh)
{
  const int row = blockIdx.x, tid = threadIdx.x;
  float4* xp = (float4*)(x + (size_t)row * DM);
  const ushort4 av = ((const ushort4*)(a + (size_t)row * DM))[tid];
  float4 xv = xp[tid];
  float4 s = make_float4(xv.x + h2f(av.x), xv.y + h2f(av.y),
                         xv.z + h2f(av.z), xv.w + h2f(av.w));
  __shared__ float red[4];
  float sum = s.x + s.y + s.z + s.w;
  for (int o = 32; o; o >>= 1) sum += __shfl_down(sum, o);
  if ((tid & 63) == 0) red[tid >> 6] = sum;
  __syncthreads();
  float mu = (red[0] + red[1] + red[2] + red[3]) * (1.f / DM);
  float dx = s.x - mu, dy = s.y - mu, dz = s.z - mu, dw = s.w - mu;
  float sq = dx * dx + dy * dy + dz * dz + dw * dw;
  for (int o = 32; o; o >>= 1) sq += __shfl_down(sq, o);
  __syncthreads();
  if ((tid & 63) == 0) red[tid >> 6] = sq;
  __syncthreads();
  float var = (red[0] + red[1] + red[2] + red[3]) * (1.f / DM);
  float rstd = rsqrtf(var + 1e-5f);
  const float4 gv = ((const float4*)g)[tid];
  const float4 bv = ((const float4*)bt)[tid];
  float4 o4 = make_float4(dx * rstd * gv.x + bv.x, dy * rstd * gv.y + bv.y,
                          dz * rstd * gv.z + bv.z, dw * rstd * gv.w + bv.w);
  xp[tid] = o4;
  ushort4 u;
  u.x = f2h(o4.x); u.y = f2h(o4.y); u.z = f2h(o4.z); u.w = f2h(o4.w);
  ((ushort4*)(xh + (size_t)row * DM))[tid] = u;
}

// ---------------- x = LayerNorm(x + p0+p1+p2+p3(fp16) + bias)*g + b ----------------
__global__ __launch_bounds__(256) void add_ln_cvt4(
    float* __restrict__ x, const unsigned short* __restrict__ p, long long pstride,
    const float* __restrict__ bias,
    const float* __restrict__ g, const float* __restrict__ bt,
    unsigned short* __restrict__ xh)
{
  const int row = blockIdx.x, tid = threadIdx.x;
  float4* xp = (float4*)(x + (size_t)row * DM);
  const float4 bb = ((const float4*)bias)[tid];
  float4 xv = xp[tid];
  float4 s = make_float4(xv.x + bb.x, xv.y + bb.y, xv.z + bb.z, xv.w + bb.w);
#pragma unroll
  for (int zz = 0; zz < 4; zz++) {
    const ushort4 a = ((const ushort4*)(p + zz * pstride + (size_t)row * DM))[tid];
    s.x += h2f(a.x); s.y += h2f(a.y); s.z += h2f(a.z); s.w += h2f(a.w);
  }
  __shared__ float red[4];
  float sum = s.x + s.y + s.z + s.w;
  for (int o = 32; o; o >>= 1) sum += __shfl_down(sum, o);
  if ((tid & 63) == 0) red[tid >> 6] = sum;
  __syncthreads();
  float mu = (red[0] + red[1] + red[2] + red[3]) * (1.f / DM);
  float dx = s.x - mu, dy = s.y - mu, dz = s.z - mu, dw = s.w - mu;
  float sq = dx * dx + dy * dy + dz * dz + dw * dw;
  for (int o = 32; o; o >>= 1) sq += __shfl_down(sq, o);
  __syncthreads();
  if ((tid & 63) == 0) red[tid >> 6] = sq;
  __syncthreads();
  float var = (red[0] + red[1] + red[2] + red[3]) * (1.f / DM);
  float rstd = rsqrtf(var + 1e-5f);
  const float4 gv = ((const float4*)g)[tid];
  const float4 bv = ((const float4*)bt)[tid];
  float4 o4 = make_float4(dx * rstd * gv.x + bv.x, dy * rstd * gv.y + bv.y,
                          dz * rstd * gv.z + bv.z, dw * rstd * gv.w + bv.w);
  xp[tid] = o4;
  ushort4 u;
  u.x = f2h(o4.x); u.y = f2h(o4.y); u.z = f2h(o4.z); u.w = f2h(o4.w);
  ((ushort4*)(xh + (size_t)row * DM))[tid] = u;
}

extern "C" void kernel_launch(void* const* d_in, const int* in_sizes, int n_in,
                              void* d_out, int out_size, void* d_ws, size_t ws_size,
                              hipStream_t stream)
{
  const float* x_in = (const float*)d_in[0];
  const int*   mask = (const int*)d_in[1];
  const float* qkv_w = (const float*)d_in[2];
  const float* r_r  = (const float*)d_in[3];
  const float* r_w  = (const float*)d_in[4];
  const float* ln1g = (const float*)d_in[5];
  const float* ln1b = (const float*)d_in[6];
  const float* ln2g = (const float*)d_in[7];
  const float* ln2b = (const float*)d_in[8];
  const float* w1   = (const float*)d_in[9];
  const float* b1   = (const float*)d_in[10];
  const float* w2   = (const float*)d_in[11];
  const float* b2   = (const float*)d_in[12];
  float* x = (float*)d_out;
  char* ws = (char*)d_ws;

  const int ROWS = NB * SEQ;  // 4096

  // layout (bytes)
  const size_t sc_off   = 0;                                     // 256 KB
  const size_t xh_off   = 0x40000;                               // 8 MB fp16 activations
  const size_t wqt_off  = xh_off + (size_t)ROWS * DM * 2;        // 6 MB fp16 qkv_w^T
  const size_t w1t_off  = wqt_off + (size_t)3 * DM * DM * 2;     // 8 MB fp16 w1^T
  const size_t w2t_off  = w1t_off + (size_t)FFN * DM * 2;        // 8 MB fp16 w2^T
  const size_t a16_off  = w2t_off + (size_t)FFN * DM * 2;        // 8 MB fp16 attn out
  const size_t qkvh_off = a16_off + (size_t)ROWS * DM * 2;       // 24 MB fp16 qkv
  const size_t e_off    = qkvh_off + (size_t)ROWS * 3 * DM * 2;

  const size_t ab_bytes = (size_t)64 * SEQ * 384 * 2;            // 25.2 MB each
  const size_t hb_bytes = (size_t)ROWS * FFN * 2;                // 32 MB
  const size_t part_off = e_off + hb_bytes;

  float* sc     = (float*)(ws + sc_off);
  unsigned short* xh = (unsigned short*)(ws + xh_off);
  unsigned short* wqt = (unsigned short*)(ws + wqt_off);
  unsigned short* w1t = (unsigned short*)(ws + w1t_off);
  unsigned short* w2t = (unsigned short*)(ws + w2t_off);
  unsigned short* a16 = (unsigned short*)(ws + a16_off);
  unsigned short* qkvh = (unsigned short*)(ws + qkvh_off);
  unsigned short* Ahat = (unsigned short*)(ws + e_off);
  unsigned short* Bhat = (unsigned short*)(ws + e_off + ab_bytes);
  unsigned short* Vt   = (unsigned short*)(ws + e_off + 2 * ab_bytes);
  unsigned short* hb = (unsigned short*)(ws + e_off);
  unsigned short* part = (unsigned short*)(ws + part_off);

  // prep: sc table (128 blocks) + x copy/fp16 shadow (4096 blocks)
  prep_kernel<<<dim3(128 + ROWS * DM / 4 / 256), 256, 0, stream>>>(sc, x_in, x, xh);

  for (int L = 0; L < NL; L++) {
    // all three weight transposes for this layer in one launch (11264 blocks)
    transpose_cvt3<<<dim3(11264), 256, 0, stream>>>(
        qkv_w + (size_t)L * DM * 3 * DM, w1 + (size_t)L * DM * FFN,
        w2 + (size_t)L * FFN * DM, wqt, w1t, w2t);

    // QKV (fp16 out): 256^2 BK32 dbuf (2 blk/CU), grid 12x16=192
    gemm256<0,0,1><<<dim3(3 * DM / 256, ROWS / 256, 1), 512, 0, stream>>>(
        xh, DM, 0, wqt, DM, 0, nullptr, qkvh, 3 * DM, 0, DM);

    // attention prep (merged) + fused attention
    build_attn<<<dim3(256 + 64, 64), 256, 0, stream>>>(
        qkvh, r_r + (size_t)L * NH * HD, r_w + (size_t)L * NH * HD, sc, Ahat, Bhat, Vt);
    attn_fused<<<dim3(SEQ / 64, 1, 64), 512, 0, stream>>>(Ahat, Bhat, Vt, mask, a16);

    add_ln_cvt<<<dim3(ROWS), 256, 0, stream>>>(x, a16, ln1g + (size_t)L * DM, ln1b + (size_t)L * DM, xh);

    // FFN1: hb(fp16) = relu(xh @ w1 + b1), grid 16x16=256
    gemm256<1,1,1><<<dim3(FFN / 256, ROWS / 256, 1), 512, 0, stream>>>(
        xh, DM, 0, w1t, DM, 0, b1 + (size_t)L * FFN, hb, FFN, 0, DM);

    // FFN2 split-K=4 (fp16 partials), grid 4x16x4=256
    gemm256<0,0,1><<<dim3(DM / 256, ROWS / 256, 4), 512, 0, stream>>>(
        hb, FFN, 1024, w2t, FFN, 1024, nullptr,
        part, DM, (long long)ROWS * DM, 1024);

    add_ln_cvt4<<<dim3(ROWS), 256, 0, stream>>>(
        x, part, (long long)ROWS * DM, b2 + (size_t)L * DM,
        ln2g + (size_t)L * DM, ln2b + (size_t)L * DM, xh);
  }
}

// Round 21
// 829.354 us; speedup vs baseline: 4.8326x; 4.8326x over previous
//
#include <hip/hip_runtime.h>

#define SEQ 512
#define DM 1024
#define NH 8
#define HD 128
#define FFN 4096
#define NL 4
#define NB 8

typedef __attribute__((ext_vector_type(8))) _Float16 half8v;
typedef __attribute__((ext_vector_type(8))) unsigned short ushort8v;
typedef __attribute__((ext_vector_type(4))) float float4v;

__device__ __forceinline__ unsigned short f2h(float f) {
  _Float16 h = (_Float16)f;
  return *(unsigned short*)&h;
}
__device__ __forceinline__ float h2f(unsigned short u) {
  _Float16 h = *(_Float16*)&u;
  return (float)h;
}

// ---------------- prep: sc table (blocks 0..127) + x copy/fp16 shadow (blocks 128..) ----------------
__global__ void prep_kernel(float* __restrict__ sc,
                            const float* __restrict__ in, float* __restrict__ xout,
                            unsigned short* __restrict__ xh) {
  if (blockIdx.x < 128) {
    int idx = blockIdx.x * 256 + threadIdx.x;
    int q = idx >> 6, c = idx & 63;
    double a = exp(-(double)c * (9.210340371976184 / 63.0));  // ln(10000)/63
    double p = (double)q * a;
    sc[q * 128 + c] = (float)sin(p);
    sc[q * 128 + 64 + c] = (float)cos(p);
  } else {
    int i = (blockIdx.x - 128) * 256 + threadIdx.x;
    float4 v = ((const float4*)in)[i];
    ((float4*)xout)[i] = v;
    ushort4 u;
    u.x = f2h(v.x); u.y = f2h(v.y); u.z = f2h(v.z); u.w = f2h(v.w);
    ((ushort4*)xh)[i] = u;
  }
}

// ---------------- batched weight transpose+cvt for one layer: qkv_w, w1, w2 ----------------
__global__ __launch_bounds__(256) void transpose_cvt3(
    const float* __restrict__ qw, const float* __restrict__ w1,
    const float* __restrict__ w2,
    unsigned short* __restrict__ wqt, unsigned short* __restrict__ w1t,
    unsigned short* __restrict__ w2t)
{
  __shared__ float t[32][33];
  int id = blockIdx.x;
  const float* in;
  unsigned short* out;
  int K, N, loc;
  if (id < 3072)      { in = qw; out = wqt; K = 1024; N = 3072; loc = id; }
  else if (id < 7168) { in = w1; out = w1t; K = 1024; N = 4096; loc = id - 3072; }
  else                { in = w2; out = w2t; K = 4096; N = 1024; loc = id - 7168; }
  int nx = N >> 5;
  int n0 = (loc % nx) * 32, k0 = (loc / nx) * 32;
  int c = threadIdx.x & 31, r = threadIdx.x >> 5;
#pragma unroll
  for (int i = 0; i < 32; i += 8)
    t[r + i][c] = in[(long long)(k0 + r + i) * N + n0 + c];
  __syncthreads();
#pragma unroll
  for (int i = 0; i < 32; i += 8)
    out[(long long)(n0 + r + i) * K + k0 + c] = f2h(t[c][r + i]);
}

// ---------------- staging: R rows x 64 cols fp16, st_16x32 swizzle, 16B DMA ----------------
template<int R, int T>
__device__ __forceinline__ void stage_tile(
    const unsigned short* __restrict__ g, long long ld, int k0,
    unsigned short* lds, int tid) {
#pragma unroll
  for (int i = 0; i < R * 64 / 8 / T; i++) {
    int p = i * T + tid;
    int row = p >> 3, cs = p & 7;
    int c = cs ^ (row & 7);
    const unsigned short* src = g + (long long)row * ld + k0 + c * 8;
    __builtin_amdgcn_global_load_lds(
        (const __attribute__((address_space(1))) void*)src,
        (__attribute__((address_space(3))) void*)(lds + p * 8),
        16, 0, 0);
  }
}

// 256 rows x 32 K-cols region; chunk swizzle c = cs ^ ((row>>1)&3); 2 loads/thread @512thr
__device__ __forceinline__ void stageK(
    const unsigned short* __restrict__ g, long long ld, int k0,
    unsigned short* lds, int tid) {
#pragma unroll
  for (int i = 0; i < 2; i++) {
    int p = i * 512 + tid;              // 0..1023 16B slots
    int row = p >> 2, cs = p & 3;
    int c = cs ^ ((row >> 1) & 3);
    const unsigned short* src = g + (long long)row * ld + k0 + c * 8;
    __builtin_amdgcn_global_load_lds(
        (const __attribute__((address_space(1))) void*)src,
        (__attribute__((address_space(3))) void*)(lds + p * 8),
        16, 0, 0);
  }
}

// ---------------- reg-staged 128x64 tile: global->VGPR then VGPR->LDS ----------------
__device__ __forceinline__ void load_stage128(
    const unsigned short* __restrict__ g, long long ld, int k0, int tid, ushort8v* v) {
#pragma unroll
  for (int i = 0; i < 2; i++) {
    int p = i * 512 + tid;
    int row = p >> 3, cs = p & 7;
    int c = cs ^ (row & 7);
    v[i] = *(const ushort8v*)(g + (long long)row * ld + k0 + c * 8);
  }
}
__device__ __forceinline__ void write_stage128(
    unsigned short* St, int tid, const ushort8v* v) {
#pragma unroll
  for (int i = 0; i < 2; i++)
    *(ushort8v*)(St + (i * 512 + tid) * 8) = v[i];
}

// ---------------- 256x256 fp16 MFMA GEMM — 4-phase K-half schedule (m201-style) ----------------
// 512 threads = 8 waves (2M x 4N); per-wave 128x64 output = 8x4 frags.
// LDS 128KB: [buf][ks][256x32] for A and B. Phases: p0=(ks0,n01) p1=(ks0,n23)
// p2=(ks1,n01) p3=(ks1,n23); 16 MFMA each. Stage schedule (regions die -> refill):
// p0: B-k1(t+1); p1: A-k0(t+2); p2: B-k0(t+2); p3: A-k1(t+2) + vmcnt(6).
template<int BIAS, int RELU, int OUTH>
__global__ __launch_bounds__(512, 2) void gemm256(
    const unsigned short* __restrict__ A, int lda, long long sAz,
    const unsigned short* __restrict__ Bt, int ldb, long long sBz,
    const float* __restrict__ bias,
    void* __restrict__ Cv, int ldc, long long sCz,
    int K) {
  __shared__ __align__(16) unsigned short As[2][2][256 * 32];
  __shared__ __align__(16) unsigned short Bs[2][2][256 * 32];
  const int tid = threadIdx.x, lane = tid & 63, w = tid >> 6;
  const int wm = w >> 2, wn = w & 3;
  const int l15 = lane & 15, l4 = lane >> 4;
  const int gx = gridDim.x, gy = gridDim.y;
  int nwg = gx * gy * gridDim.z;
  int lin = (blockIdx.z * gy + blockIdx.y) * gx + blockIdx.x;
  int swz = (lin & 7) * (nwg >> 3) + (lin >> 3);
  int bx = swz % gx;
  int t2 = swz / gx;
  int by = t2 % gy;
  int z  = t2 / gy;
  const unsigned short* Ag = A + (long long)z * sAz + (long long)by * 256 * lda;
  const unsigned short* Bg = Bt + (long long)z * sBz + (long long)bx * 256 * ldb;

  float4v acc[8][4] = {};
  const int nt = K >> 6;
  // prologue: tile0 all 4 regions; tile1 A-k0,B-k0,A-k1 (B-k1 staged at t=0 ph0)
  stageK(Ag, lda, 0,  As[0][0], tid); stageK(Bg, ldb, 0,  Bs[0][0], tid);
  stageK(Ag, lda, 32, As[0][1], tid); stageK(Bg, ldb, 32, Bs[0][1], tid);
  stageK(Ag, lda, 64, As[1][0], tid); stageK(Bg, ldb, 64, Bs[1][0], tid);
  stageK(Ag, lda, 96, As[1][1], tid);
  asm volatile("s_waitcnt vmcnt(6)" ::: "memory");
  asm volatile("s_barrier" ::: "memory");

  half8v af[8], bf[4];
  for (int t = 0; t < nt; t++) {
    const int cur = t & 1, nxt = cur ^ 1;
    // ---------------- phase 0: (ks0, n0-1) ----------------
#pragma unroll
    for (int m = 0; m < 8; m++) {
      int row = wm * 128 + m * 16 + l15;
      af[m] = *(const half8v*)&As[cur][0][row * 32 + (l4 ^ ((row >> 1) & 3)) * 8];
    }
#pragma unroll
    for (int n = 0; n < 2; n++) {
      int row = wn * 64 + n * 16 + l15;
      bf[n] = *(const half8v*)&Bs[cur][0][row * 32 + (l4 ^ ((row >> 1) & 3)) * 8];
    }
    if (t + 1 < nt) stageK(Bg, ldb, ((t + 1) << 6) + 32, Bs[nxt][1], tid);
    asm volatile("s_barrier" ::: "memory");
    __builtin_amdgcn_s_setprio(1);
#pragma unroll
    for (int m = 0; m < 8; m++)
#pragma unroll
      for (int n = 0; n < 2; n++)
        acc[m][n] = __builtin_amdgcn_mfma_f32_16x16x32_f16(af[m], bf[n], acc[m][n], 0, 0, 0);
    __builtin_amdgcn_s_setprio(0);
    asm volatile("s_barrier" ::: "memory");
    // ---------------- phase 1: (ks0, n2-3) ----------------
#pragma unroll
    for (int n = 0; n < 2; n++) {
      int row = wn * 64 + (2 + n) * 16 + l15;
      bf[2 + n] = *(const half8v*)&Bs[cur][0][row * 32 + (l4 ^ ((row >> 1) & 3)) * 8];
    }
    if (t + 2 < nt) stageK(Ag, lda, (t + 2) << 6, As[cur][0], tid);
    asm volatile("s_barrier" ::: "memory");
    __builtin_amdgcn_s_setprio(1);
#pragma unroll
    for (int m = 0; m < 8; m++)
#pragma unroll
      for (int n = 0; n < 2; n++)
        acc[m][2 + n] = __builtin_amdgcn_mfma_f32_16x16x32_f16(af[m], bf[2 + n], acc[m][2 + n], 0, 0, 0);
    __builtin_amdgcn_s_setprio(0);
    asm volatile("s_barrier" ::: "memory");
    // ---------------- phase 2: (ks1, n0-1) ----------------
#pragma unroll
    for (int m = 0; m < 8; m++) {
      int row = wm * 128 + m * 16 + l15;
      af[m] = *(const half8v*)&As[cur][1][row * 32 + (l4 ^ ((row >> 1) & 3)) * 8];
    }
#pragma unroll
    for (int n = 0; n < 2; n++) {
      int row = wn * 64 + n * 16 + l15;
      bf[n] = *(const half8v*)&Bs[cur][1][row * 32 + (l4 ^ ((row >> 1) & 3)) * 8];
    }
    if (t + 2 < nt) stageK(Bg, ldb, (t + 2) << 6, Bs[cur][0], tid);
    asm volatile("s_barrier" ::: "memory");
    __builtin_amdgcn_s_setprio(1);
#pragma unroll
    for (int m = 0; m < 8; m++)
#pragma unroll
      for (int n = 0; n < 2; n++)
        acc[m][n] = __builtin_amdgcn_mfma_f32_16x16x32_f16(af[m], bf[n], acc[m][n], 0, 0, 0);
    __builtin_amdgcn_s_setprio(0);
    asm volatile("s_barrier" ::: "memory");
    // ---------------- phase 3: (ks1, n2-3) ----------------
#pragma unroll
    for (int n = 0; n < 2; n++) {
      int row = wn * 64 + (2 + n) * 16 + l15;
      bf[2 + n] = *(const half8v*)&Bs[cur][1][row * 32 + (l4 ^ ((row >> 1) & 3)) * 8];
    }
    if (t + 2 < nt) {
      stageK(Ag, lda, ((t + 2) << 6) + 32, As[cur][1], tid);
      asm volatile("s_waitcnt vmcnt(6)" ::: "memory");
    } else {
      asm volatile("s_waitcnt vmcnt(0)" ::: "memory");
    }
    asm volatile("s_barrier" ::: "memory");
    __builtin_amdgcn_s_setprio(1);
#pragma unroll
    for (int m = 0; m < 8; m++)
#pragma unroll
      for (int n = 0; n < 2; n++)
        acc[m][2 + n] = __builtin_amdgcn_mfma_f32_16x16x32_f16(af[m], bf[2 + n], acc[m][2 + n], 0, 0, 0);
    __builtin_amdgcn_s_setprio(0);
    asm volatile("s_barrier" ::: "memory");
  }
#pragma unroll
  for (int n = 0; n < 4; n++) {
    int ccol = bx * 256 + wn * 64 + n * 16 + l15;
    float bv = BIAS ? bias[ccol] : 0.f;
#pragma unroll
    for (int m = 0; m < 8; m++) {
      int crow0 = by * 256 + wm * 128 + m * 16 + l4 * 4;
#pragma unroll
      for (int j = 0; j < 4; j++) {
        float v = acc[m][n][j] + bv;
        if (RELU) v = fmaxf(v, 0.f);
        long long off = (long long)z * sCz + (long long)(crow0 + j) * ldc + ccol;
        if (OUTH) ((unsigned short*)Cv)[off] = f2h(v);
        else      ((float*)Cv)[off] = v;
      }
    }
  }
}

// ---------------- merged attention prep: build_aug (bx<256) + V transpose (bx>=256) ----------------
__global__ __launch_bounds__(256) void build_attn(
    const unsigned short* __restrict__ qkv_h,
    const float* __restrict__ rr, const float* __restrict__ rw,
    const float* __restrict__ sc,
    unsigned short* __restrict__ Ahat, unsigned short* __restrict__ Bhat,
    unsigned short* __restrict__ Vt)
{
  const int z = blockIdx.y, b = z >> 3, h = z & 7;
  if (blockIdx.x < 256) {
    const int r = threadIdx.x >> 7, lane = threadIdx.x & 127;
    const int q = blockIdx.x * 2 + r;
    __shared__ float Qf[2][128], Kf[2][128], SC[2][128];
    const unsigned short* row = qkv_h + ((long long)(b * SEQ + q)) * 3072 + h * HD;
    float qv = h2f(row[lane]);
    float kv = h2f(row[DM + lane]);
    Qf[r][lane] = qv + rw[h * HD + lane];
    Kf[r][lane] = kv;
    SC[r][lane] = sc[q * 128 + lane];
    __syncthreads();
    unsigned short* Arow = Ahat + ((long long)z * SEQ + q) * 384;
    unsigned short* Brow = Bhat + ((long long)z * SEQ + q) * 384;
    Arow[lane] = f2h(qv + rr[h * HD + lane]);
    Brow[lane] = f2h(kv);
    if (lane < 64) {
      float S = SC[r][lane], C = SC[r][64 + lane];
      Arow[128 + lane] = f2h(Qf[r][lane] * C + Qf[r][64 + lane] * S);
      Arow[256 + lane] = f2h(S);
      Brow[128 + lane] = f2h(S);
      Brow[256 + lane] = f2h(Kf[r][lane] * C + Kf[r][64 + lane] * S);
    } else {
      int c = lane - 64;
      float S = SC[r][c], C = SC[r][lane];
      Arow[192 + c] = f2h(Qf[r][lane] * C - Qf[r][c] * S);
      Arow[320 + c] = f2h(C);
      Brow[192 + c] = f2h(C);
      Brow[320 + c] = f2h(Kf[r][lane] * C - Kf[r][c] * S);
    }
  } else {
    __shared__ unsigned short t[32][33];
    int tile = blockIdx.x - 256;            // 64 tiles: 4 (d) x 16 (j)
    const int d0 = (tile & 3) * 32, j0 = (tile >> 2) * 32;
    const int c = threadIdx.x & 31, r = threadIdx.x >> 5;
#pragma unroll
    for (int i = 0; i < 32; i += 8)
      t[r + i][c] = qkv_h[((long long)(b * SEQ + j0 + r + i)) * 3072 + 2 * DM + h * HD + d0 + c];
    __syncthreads();
#pragma unroll
    for (int i = 0; i < 32; i += 8)
      Vt[(long long)z * HD * SEQ + (long long)(d0 + r + i) * SEQ + j0 + c] = t[c][r + i];
  }
}

// ---------------- fused attention: reg-staged pipeline, raw barriers, no vmcnt drain ----------------
__global__ __launch_bounds__(512, 4) void attn_fused(
    const unsigned short* __restrict__ Ahat,
    const unsigned short* __restrict__ Bhat,
    const unsigned short* __restrict__ Vt,
    const int* __restrict__ mask,
    unsigned short* __restrict__ out)
{
  __shared__ __align__(16) unsigned short S[64 * 512];
  __shared__ __align__(16) unsigned short St[128 * 64];
  const int tid = threadIdx.x, lane = tid & 63, w = tid >> 6;
  const int wr = w >> 1, wc = w & 1;
  const int l15 = lane & 15, l4 = lane >> 4;
  int lin = blockIdx.z * gridDim.x + blockIdx.x;
  int nwg = gridDim.x * gridDim.z;
  int swz = (lin & 7) * (nwg >> 3) + (lin >> 3);
  int qt = swz % gridDim.x, z = swz / gridDim.x;
  const int b = z >> 3, h = z & 7;
  const int q0 = qt * 64;

  half8v qf[12];
  {
    const unsigned short* Ar = Ahat + ((long long)z * SEQ + q0 + wr * 16 + l15) * 384;
#pragma unroll
    for (int k = 0; k < 12; k++)
      qf[k] = *(const half8v*)&Ar[k * 32 + l4 * 8];
  }

  // ---- phase 1: S (64 x 512) fp16 into XOR-swizzled LDS; B-tiles reg-staged ----
  ushort8v stg[2];
  load_stage128(Bhat + ((long long)z * SEQ) * 384, 384, 0, tid, stg);
#pragma unroll
  for (int jt = 0; jt < 4; jt++) {
    float4v acc[4] = {};
#pragma unroll
    for (int k6 = 0; k6 < 6; k6++) {
      __builtin_amdgcn_s_barrier();                 // St free (prev compute done)
      write_stage128(St, tid, stg);
      int ns = jt * 6 + k6 + 1;
      if (ns < 24) {
        const unsigned short* Bg = Bhat + ((long long)z * SEQ + (ns / 6) * 128) * 384;
        load_stage128(Bg, 384, (ns % 6) * 64, tid, stg);
      }
      asm volatile("s_waitcnt lgkmcnt(0)" ::: "memory");
      __builtin_amdgcn_s_barrier();                 // St visible (vmcnt NOT drained)
      __builtin_amdgcn_s_setprio(1);
#pragma unroll
      for (int kk = 0; kk < 2; kk++) {
        int kidx = k6 * 2 + kk;
#pragma unroll
        for (int n = 0; n < 4; n++) {
          int row = wc * 64 + n * 16 + l15;
          int cs = (kk * 4 + l4) ^ (row & 7);
          half8v bf = *(const half8v*)&St[row * 64 + cs * 8];
          acc[n] = __builtin_amdgcn_mfma_f32_16x16x32_f16(qf[kidx], bf, acc[n], 0, 0, 0);
        }
      }
      __builtin_amdgcn_s_setprio(0);
    }
#pragma unroll
    for (int n = 0; n < 4; n++) {
      int col = jt * 128 + wc * 64 + n * 16 + l15;
#pragma unroll
      for (int j = 0; j < 4; j++) {
        int row = wr * 16 + l4 * 4 + j;
        int byte = (row * 512 + col) * 2;
        byte ^= (row & 7) << 4;
        *(unsigned short*)((char*)S + byte) = f2h(acc[n][j]);
      }
    }
  }

  // prefetch V tile 0 (latency hides under softmax)
  const unsigned short* Vg = Vt + (long long)z * HD * SEQ;
  load_stage128(Vg, 512, 0, tid, stg);

  asm volatile("s_waitcnt lgkmcnt(0)" ::: "memory");  // S writes done
  __builtin_amdgcn_s_barrier();

  // ---- phase 2: mask bias + in-LDS softmax (interleaved, bank-friendly) ----
  float* bias = (float*)St;          // 512 floats
  float* Linv = (float*)St + 512;    // 64 floats
  if (tid < 128) {
    int4 mk = ((const int4*)(mask + (size_t)b * SEQ))[tid];
    float4 bv;
    bv.x = mk.x ? 0.f : -1e30f;
    bv.y = mk.y ? 0.f : -1e30f;
    bv.z = mk.z ? 0.f : -1e30f;
    bv.w = mk.w ? 0.f : -1e30f;
    ((float4*)bias)[tid] = bv;
  }
  asm volatile("s_waitcnt lgkmcnt(0)" ::: "memory");
  __builtin_amdgcn_s_barrier();
  {
    const int row = tid >> 3;
    const int c8 = tid & 7;
    float mx = -1e30f;
#pragma unroll
    for (int i = 0; i < 8; i++) {
      int col = i * 64 + c8 * 8;
      int byte = (row * 512 + col) * 2;
      byte ^= (row & 7) << 4;
      ushort8v u = *(const ushort8v*)((const char*)S + byte);
      const float* bp = bias + col;
#pragma unroll
      for (int e = 0; e < 8; e++)
        mx = fmaxf(mx, h2f(u[e]) + bp[e]);
    }
    mx = fmaxf(mx, __shfl_xor(mx, 1));
    mx = fmaxf(mx, __shfl_xor(mx, 2));
    mx = fmaxf(mx, __shfl_xor(mx, 4));
    float sum = 0.f;
#pragma unroll
    for (int i = 0; i < 8; i++) {
      int col = i * 64 + c8 * 8;
      int byte = (row * 512 + col) * 2;
      byte ^= (row & 7) << 4;
      ushort8v u = *(const ushort8v*)((const char*)S + byte);
      const float* bp = bias + col;
#pragma unroll
      for (int e = 0; e < 8; e++) {
        float ev = __expf(h2f(u[e]) + bp[e] - mx);
        sum += ev;
        u[e] = f2h(ev);
      }
      *(ushort8v*)((char*)S + byte) = u;
    }
    sum += __shfl_xor(sum, 1);
    sum += __shfl_xor(sum, 2);
    sum += __shfl_xor(sum, 4);
    if (c8 == 0) Linv[row] = 1.f / sum;
  }
  asm volatile("s_waitcnt lgkmcnt(0)" ::: "memory");
  __builtin_amdgcn_s_barrier();
  float rs[4];
#pragma unroll
  for (int j = 0; j < 4; j++) rs[j] = Linv[wr * 16 + l4 * 4 + j];
  asm volatile("s_waitcnt lgkmcnt(0)" ::: "memory");  // Linv reads complete before St reuse

  // ---- phase 3: O = P-hat @ Vt^T; V-tiles reg-staged ----
  float4v oacc[4] = {};
#pragma unroll
  for (int k8 = 0; k8 < 8; k8++) {
    __builtin_amdgcn_s_barrier();                 // St free
    write_stage128(St, tid, stg);
    if (k8 + 1 < 8) load_stage128(Vg, 512, (k8 + 1) * 64, tid, stg);
    asm volatile("s_waitcnt lgkmcnt(0)" ::: "memory");
    __builtin_amdgcn_s_barrier();                 // St visible
    __builtin_amdgcn_s_setprio(1);
#pragma unroll
    for (int kk = 0; kk < 2; kk++) {
      int prow = wr * 16 + l15;
      int pb = (prow * 512 + k8 * 64 + kk * 32 + l4 * 8) * 2;
      pb ^= (prow & 7) << 4;
      half8v af = *(const half8v*)((const char*)S + pb);
#pragma unroll
      for (int n = 0; n < 4; n++) {
        int row = wc * 64 + n * 16 + l15;
        int cs = (kk * 4 + l4) ^ (row & 7);
        half8v bf = *(const half8v*)&St[row * 64 + cs * 8];
        oacc[n] = __builtin_amdgcn_mfma_f32_16x16x32_f16(af, bf, oacc[n], 0, 0, 0);
      }
    }
    __builtin_amdgcn_s_setprio(0);
  }
#pragma unroll
  for (int j = 0; j < 4; j++) {
    int row = q0 + wr * 16 + l4 * 4 + j;
#pragma unroll
    for (int n = 0; n < 4; n++) {
      int col = h * HD + wc * 64 + n * 16 + l15;
      out[((long long)(b * SEQ + row)) * DM + col] = f2h(oacc[n][j] * rs[j]);
    }
  }
}

// ---------------- x = LayerNorm(x + a16)*g + b, in-place, + fp16 shadow ----------------
__global__ __launch_bounds__(256) void add_ln_cvt(
    float* __restrict__ x, const unsigned short* __restrict__ a,
    const float* __restrict__ g, const float* __restrict__ bt,
    unsigned short* __restrict__ xh)
{
  const int row = blockIdx.x, tid = threadIdx.x;
  float4* xp = (float4*)(x + (size_t)row * DM);
  const ushort4 av = ((const ushort4*)(a + (size_t)row * DM))[tid];
  float4 xv = xp[tid];
  float4 s = make_float4(xv.x + h2f(av.x), xv.y + h2f(av.y),
                         xv.z + h2f(av.z), xv.w + h2f(av.w));
  __shared__ float red[4];
  float sum = s.x + s.y + s.z + s.w;
  for (int o = 32; o; o >>= 1) sum += __shfl_down(sum, o);
  if ((tid & 63) == 0) red[tid >> 6] = sum;
  __syncthreads();
  float mu = (red[0] + red[1] + red[2] + red[3]) * (1.f / DM);
  float dx = s.x - mu, dy = s.y - mu, dz = s.z - mu, dw = s.w - mu;
  float sq = dx * dx + dy * dy + dz * dz + dw * dw;
  for (int o = 32; o; o >>= 1) sq += __shfl_down(sq, o);
  __syncthreads();
  if ((tid & 63) == 0) red[tid >> 6] = sq;
  __syncthreads();
  float var = (red[0] + red[1] + red[2] + red[3]) * (1.f / DM);
  float rstd = rsqrtf(var + 1e-5f);
  const float4 gv = ((const float4*)g)[tid];
  const float4 bv = ((const float4*)bt)[tid];
  float4 o4 = make_float4(dx * rstd * gv.x + bv.x, dy * rstd * gv.y + bv.y,
                          dz * rstd * gv.z + bv.z, dw * rstd * gv.w + bv.w);
  xp[tid] = o4;
  ushort4 u;
  u.x = f2h(o4.x); u.y = f2h(o4.y); u.z = f2h(o4.z); u.w = f2h(o4.w);
  ((ushort4*)(xh + (size_t)row * DM))[tid] = u;
}

// ---------------- x = LayerNorm(x + p0+p1+p2+p3(fp16) + bias)*g + b ----------------
__global__ __launch_bounds__(256) void add_ln_cvt4(
    float* __restrict__ x, const unsigned short* __restrict__ p, long long pstride,
    const float* __restrict__ bias,
    const float* __restrict__ g, const float* __restrict__ bt,
    unsigned short* __restrict__ xh)
{
  const int row = blockIdx.x, tid = threadIdx.x;
  float4* xp = (float4*)(x + (size_t)row * DM);
  const float4 bb = ((const float4*)bias)[tid];
  float4 xv = xp[tid];
  float4 s = make_float4(xv.x + bb.x, xv.y + bb.y, xv.z + bb.z, xv.w + bb.w);
#pragma unroll
  for (int zz = 0; zz < 4; zz++) {
    const ushort4 a = ((const ushort4*)(p + zz * pstride + (size_t)row * DM))[tid];
    s.x += h2f(a.x); s.y += h2f(a.y); s.z += h2f(a.z); s.w += h2f(a.w);
  }
  __shared__ float red[4];
  float sum = s.x + s.y + s.z + s.w;
  for (int o = 32; o; o >>= 1) sum += __shfl_down(sum, o);
  if ((tid & 63) == 0) red[tid >> 6] = sum;
  __syncthreads();
  float mu = (red[0] + red[1] + red[2] + red[3]) * (1.f / DM);
  float dx = s.x - mu, dy = s.y - mu, dz = s.z - mu, dw = s.w - mu;
  float sq = dx * dx + dy * dy + dz * dz + dw * dw;
  for (int o = 32; o; o >>= 1) sq += __shfl_down(sq, o);
  __syncthreads();
  if ((tid & 63) == 0) red[tid >> 6] = sq;
  __syncthreads();
  float var = (red[0] + red[1] + red[2] + red[3]) * (1.f / DM);
  float rstd = rsqrtf(var + 1e-5f);
  const float4 gv = ((const float4*)g)[tid];
  const float4 bv = ((const float4*)bt)[tid];
  float4 o4 = make_float4(dx * rstd * gv.x + bv.x, dy * rstd * gv.y + bv.y,
                          dz * rstd * gv.z + bv.z, dw * rstd * gv.w + bv.w);
  xp[tid] = o4;
  ushort4 u;
  u.x = f2h(o4.x); u.y = f2h(o4.y); u.z = f2h(o4.z); u.w = f2h(o4.w);
  ((ushort4*)(xh + (size_t)row * DM))[tid] = u;
}

extern "C" void kernel_launch(void* const* d_in, const int* in_sizes, int n_in,
                              void* d_out, int out_size, void* d_ws, size_t ws_size,
                              hipStream_t stream)
{
  const float* x_in = (const float*)d_in[0];
  const int*   mask = (const int*)d_in[1];
  const float* qkv_w = (const float*)d_in[2];
  const float* r_r  = (const float*)d_in[3];
  const float* r_w  = (const float*)d_in[4];
  const float* ln1g = (const float*)d_in[5];
  const float* ln1b = (const float*)d_in[6];
  const float* ln2g = (const float*)d_in[7];
  const float* ln2b = (const float*)d_in[8];
  const float* w1   = (const float*)d_in[9];
  const float* b1   = (const float*)d_in[10];
  const float* w2   = (const float*)d_in[11];
  const float* b2   = (const float*)d_in[12];
  float* x = (float*)d_out;
  char* ws = (char*)d_ws;

  const int ROWS = NB * SEQ;  // 4096

  // layout (bytes)
  const size_t sc_off   = 0;                                     // 256 KB
  const size_t xh_off   = 0x40000;                               // 8 MB fp16 activations
  const size_t wqt_off  = xh_off + (size_t)ROWS * DM * 2;        // 6 MB fp16 qkv_w^T
  const size_t w1t_off  = wqt_off + (size_t)3 * DM * DM * 2;     // 8 MB fp16 w1^T
  const size_t w2t_off  = w1t_off + (size_t)FFN * DM * 2;        // 8 MB fp16 w2^T
  const size_t a16_off  = w2t_off + (size_t)FFN * DM * 2;        // 8 MB fp16 attn out
  const size_t qkvh_off = a16_off + (size_t)ROWS * DM * 2;       // 24 MB fp16 qkv
  const size_t e_off    = qkvh_off + (size_t)ROWS * 3 * DM * 2;

  const size_t ab_bytes = (size_t)64 * SEQ * 384 * 2;            // 25.2 MB each
  const size_t hb_bytes = (size_t)ROWS * FFN * 2;                // 32 MB
  const size_t part_off = e_off + hb_bytes;

  float* sc     = (float*)(ws + sc_off);
  unsigned short* xh = (unsigned short*)(ws + xh_off);
  unsigned short* wqt = (unsigned short*)(ws + wqt_off);
  unsigned short* w1t = (unsigned short*)(ws + w1t_off);
  unsigned short* w2t = (unsigned short*)(ws + w2t_off);
  unsigned short* a16 = (unsigned short*)(ws + a16_off);
  unsigned short* qkvh = (unsigned short*)(ws + qkvh_off);
  unsigned short* Ahat = (unsigned short*)(ws + e_off);
  unsigned short* Bhat = (unsigned short*)(ws + e_off + ab_bytes);
  unsigned short* Vt   = (unsigned short*)(ws + e_off + 2 * ab_bytes);
  unsigned short* hb = (unsigned short*)(ws + e_off);
  unsigned short* part = (unsigned short*)(ws + part_off);

  // prep: sc table (128 blocks) + x copy/fp16 shadow (4096 blocks)
  prep_kernel<<<dim3(128 + ROWS * DM / 4 / 256), 256, 0, stream>>>(sc, x_in, x, xh);

  for (int L = 0; L < NL; L++) {
    // all three weight transposes for this layer in one launch (11264 blocks)
    transpose_cvt3<<<dim3(11264), 256, 0, stream>>>(
        qkv_w + (size_t)L * DM * 3 * DM, w1 + (size_t)L * DM * FFN,
        w2 + (size_t)L * FFN * DM, wqt, w1t, w2t);

    // QKV (fp16 out): 256^2 4-phase, grid 12x16=192
    gemm256<0,0,1><<<dim3(3 * DM / 256, ROWS / 256, 1), 512, 0, stream>>>(
        xh, DM, 0, wqt, DM, 0, nullptr, qkvh, 3 * DM, 0, DM);

    // attention prep (merged) + fused attention
    build_attn<<<dim3(256 + 64, 64), 256, 0, stream>>>(
        qkvh, r_r + (size_t)L * NH * HD, r_w + (size_t)L * NH * HD, sc, Ahat, Bhat, Vt);
    attn_fused<<<dim3(SEQ / 64, 1, 64), 512, 0, stream>>>(Ahat, Bhat, Vt, mask, a16);

    add_ln_cvt<<<dim3(ROWS), 256, 0, stream>>>(x, a16, ln1g + (size_t)L * DM, ln1b + (size_t)L * DM, xh);

    // FFN1: hb(fp16) = relu(xh @ w1 + b1), 256^2 4-phase, grid 16x16=256
    gemm256<1,1,1><<<dim3(FFN / 256, ROWS / 256, 1), 512, 0, stream>>>(
        xh, DM, 0, w1t, DM, 0, b1 + (size_t)L * FFN, hb, FFN, 0, DM);

    // FFN2 split-K=4 (fp16 partials), 256^2 4-phase, grid 4x16x4=256
    gemm256<0,0,1><<<dim3(DM / 256, ROWS / 256, 4), 512, 0, stream>>>(
        hb, FFN, 1024, w2t, FFN, 1024, nullptr,
        part, DM, (long long)ROWS * DM, 1024);

    add_ln_cvt4<<<dim3(ROWS), 256, 0, stream>>>(
        x, part, (long long)ROWS * DM, b2 + (size_t)L * DM,
        ln2g + (size_t)L * DM, ln2b + (size_t)L * DM, xh);
  }
}